// Round 10
// baseline (228.639 us; speedup 1.0000x reference)
//
#include <hip/hip_runtime.h>

// Problem constants: S=128, D=512, H=8, W=64, NUM=16, SCALE=sqrt(8)
// All inputs and outputs fp32 (reference dtypes); fp32 compute throughout.
// Frozen empirical facts (r0-r9): XT[k][*] k-major transpose staging is the
// fast GEMM staging idiom; fused packaging (proj2+scores one dispatch) worth
// ~25 us; scores occupancy NOT the bottleneck (r4); barriers/phase-lock NOT
// the bottleneck (r9); nt+HALF-line stores regress (r6, RMW); full-line 1KB
// wave stores win (r7); proj4 at 2 blocks/CU wins (r8).
// This round's single variable: nt on the FULL-LINE scores stores only.
// r6's regression mechanism (partial-line RMW under L2 bypass) doesn't apply
// to full-line stores; nt avoids 134 MB of dirty-line L2 churn — the fill
// kernel (6.7 TB/s writer) is exactly this path. proj2/k_res stores stay
// cached (partial-line).
#define INV_SCALE 0.35355339059327373f
#define LOG2E 1.4426950408889634f

typedef float nat_f4 __attribute__((ext_vector_type(4)));

struct Proj4Args {
  const float* x[4];
  const float* w[4];
  const float* b[4];
  float* y[4];
};

// ---------------------------------------------------------------------------
// Stage-1 projection GEMM, 512 blocks (r8 verbatim): blk = (p<<7)|(dt<<1)|sh.
// ---------------------------------------------------------------------------
__global__ __launch_bounds__(256) void proj4_kernel(Proj4Args A) {
  __shared__ float SH[6176];  // 4096 (WL 8x512) + 2080 (XT[32][65])
  const int blk = blockIdx.x;
  const int p = blk >> 7;
  const int dbase = ((blk >> 1) & 63) * 8;
  const int shalf = (blk & 1) * 64;
  const int t = threadIdx.x;
  const int s = t & 63;
  const int g = t >> 6;  // wave id; di pair = g*2 (wave-uniform)
  float* WL = SH;
  float(*XT)[65] = (float(*)[65])(SH + 4096);
  {
    const float4* wg = (const float4*)(A.w[p] + dbase * 512);
    float4* wl4 = (float4*)WL;
#pragma unroll
    for (int r = 0; r < 4; ++r) wl4[t + r * 256] = wg[t + r * 256];
  }
  const float* xg = A.x[p] + shalf * 512;  // this block's 64 rows
  const int row = t >> 3;  // 0..31; +32 covers rows 0..63
  const int col = t & 7;   // float4 column within the 32-k chunk
  float acc[2] = {0.f, 0.f};
  float4 pre[2];
#pragma unroll
  for (int r = 0; r < 2; ++r)
    pre[r] = ((const float4*)(xg + (row + r * 32) * 512))[col];  // chunk 0
  for (int c = 0; c < 16; ++c) {
    __syncthreads();  // also covers the W stage at c==0
#pragma unroll
    for (int r = 0; r < 2; ++r) {
      float4 f = pre[r];
      int rr = row + r * 32;
      XT[col * 4 + 0][rr] = f.x;
      XT[col * 4 + 1][rr] = f.y;
      XT[col * 4 + 2][rr] = f.z;
      XT[col * 4 + 3][rr] = f.w;
    }
    __syncthreads();
    if (c + 1 < 16) {
#pragma unroll
      for (int r = 0; r < 2; ++r)
        pre[r] = ((const float4*)(xg + (row + r * 32) * 512))[(c + 1) * 8 + col];
    }
#pragma unroll
    for (int k4 = 0; k4 < 8; ++k4) {
      float xv0 = XT[k4 * 4 + 0][s];
      float xv1 = XT[k4 * 4 + 1][s];
      float xv2 = XT[k4 * 4 + 2][s];
      float xv3 = XT[k4 * 4 + 3][s];
#pragma unroll
      for (int di = 0; di < 2; ++di) {
        // wave-uniform address -> LDS broadcast read (free)
        const float4 wv =
            *(const float4*)&WL[(g * 2 + di) * 512 + c * 32 + k4 * 4];
        acc[di] = fmaf(wv.x, xv0, acc[di]);
        acc[di] = fmaf(wv.y, xv1, acc[di]);
        acc[di] = fmaf(wv.z, xv2, acc[di]);
        acc[di] = fmaf(wv.w, xv3, acc[di]);
      }
    }
  }
  const float* bp = A.b[p] + dbase + g * 2;
  *(float2*)(A.y[p] + (shalf + s) * 512 + dbase + g * 2) =
      make_float2(acc[0] + bp[0], acc[1] + bp[1]);
}

// ---------------------------------------------------------------------------
// GEMM body for proj2 (CHUNK=16 instantiation, r7 verbatim).
// ---------------------------------------------------------------------------
template <int CHUNK>
__device__ __forceinline__ void gemm8_body(const float* xg, const float* wg_p,
                                           const float* bp, int dbase, int t,
                                           float* SH, float o[4]) {
  const int s = t & 127;
  const int h = t >> 7;
  float* WL = SH;                                // [8][512] = 4096 floats
  float(*XT)[129] = (float(*)[129])(SH + 4096);  // [CHUNK][129]
  {
    const float4* wg = (const float4*)(wg_p + dbase * 512);
    float4* wl4 = (float4*)WL;
#pragma unroll
    for (int r = 0; r < 4; ++r) wl4[t + r * 256] = wg[t + r * 256];
  }
  constexpr int C4 = CHUNK / 4;     // float4 cols per chunk row
  constexpr int RPT = C4 / 2;       // row-groups per thread
  constexpr int NCH = 512 / CHUNK;  // number of k chunks
  constexpr int RSTEP = 256 / C4;   // row stride between r-groups
  const int row = t / C4;
  const int col = t % C4;
  float acc[4] = {0.f, 0.f, 0.f, 0.f};
  float4 pre[RPT];
#pragma unroll
  for (int r = 0; r < RPT; ++r)
    pre[r] = ((const float4*)(xg + (row + r * RSTEP) * 512))[col];  // chunk 0
  for (int c = 0; c < NCH; ++c) {
    __syncthreads();  // also covers the W stage at c==0
#pragma unroll
    for (int r = 0; r < RPT; ++r) {
      float4 f = pre[r];
      int rr = row + r * RSTEP;
      XT[col * 4 + 0][rr] = f.x;
      XT[col * 4 + 1][rr] = f.y;
      XT[col * 4 + 2][rr] = f.z;
      XT[col * 4 + 3][rr] = f.w;
    }
    __syncthreads();
    if (c + 1 < NCH) {
#pragma unroll
      for (int r = 0; r < RPT; ++r)
        pre[r] =
            ((const float4*)(xg + (row + r * RSTEP) * 512))[(c + 1) * C4 + col];
    }
#pragma unroll
    for (int k4 = 0; k4 < C4; ++k4) {
      float xv0 = XT[k4 * 4 + 0][s];
      float xv1 = XT[k4 * 4 + 1][s];
      float xv2 = XT[k4 * 4 + 2][s];
      float xv3 = XT[k4 * 4 + 3][s];
#pragma unroll
      for (int di = 0; di < 4; ++di) {
        // wave-uniform address -> LDS broadcast read (free)
        const float4 wv =
            *(const float4*)&WL[(h * 4 + di) * 512 + c * CHUNK + k4 * 4];
        acc[di] = fmaf(wv.x, xv0, acc[di]);
        acc[di] = fmaf(wv.y, xv1, acc[di]);
        acc[di] = fmaf(wv.z, xv2, acc[di]);
        acc[di] = fmaf(wv.w, xv3, acc[di]);
      }
    }
  }
#pragma unroll
  for (int di = 0; di < 4; ++di) o[di] = acc[di] + bp[dbase + h * 4 + di];
}

// ---------------------------------------------------------------------------
// Fused second launch.
//   blocks 0..255      -> stage-2 projection + DIRECT final-output epilogue
//   blocks 256..2303   -> scores (softmax att), needs stage-1 only
// ---------------------------------------------------------------------------
struct FusedArgs {
  const float* w2[4];  // Wvo,Wqo,Wao,Wko
  const float* b2[4];
  const float* vp;
  const float* qp;
  const float* ap;
  const float* kp;
  float* out;
};

__device__ __forceinline__ void proj2_direct_body(const FusedArgs& F, int blk,
                                                  int t, float* SH) {
  const int p = blk >> 6;
  const int dbase = (blk & 63) * 8;
  const float* xsrc[4] = {F.vp, F.qp, F.ap, F.kp};
  float o[4];
  gemm8_body<16>(xsrc[p], F.w2[p], F.b2[p], dbase, t, SH, o);
  const int s = t & 127;
  const int h = t >> 7;
  const int c_head = dbase >> 6;        // head index of this d-tile
  const int i0 = (dbase & 63) + h * 4;  // within-head coordinate base
  if (p == 3) {
    // k_res at flat offset 196608: [s, w*8 + head] — scattered, keep cached
#pragma unroll
    for (int di = 0; di < 4; ++di)
      F.out[196608 + s * 512 + (i0 + di) * 8 + c_head] = o[di];
    return;  // p is block-uniform: no divergent-barrier hazard
  }
  const float* fac = (p == 0) ? F.vp : (p == 1) ? F.qp : F.kp;
  const float* S0 = (p == 0) ? F.qp : F.vp;
  const float* S1 = (p == 2) ? F.qp : F.kp;
  __syncthreads();  // all GEMM LDS reads done; reuse SH
  float* Sm = SH;   // [2][128][8] = 2048 floats
#pragma unroll
  for (int m = 0; m < 2; ++m) {
    const float* M = m ? S1 : S0;
#pragma unroll
    for (int cc = 0; cc < 4; ++cc) {
      const int c = h * 4 + cc;
      const float4* r4 = (const float4*)(M + s * 512 + c * 64);
      float sum = 0.f;
#pragma unroll
      for (int u = 0; u < 16; ++u) {
        float4 f = r4[u];
        sum += (f.x + f.y) + (f.z + f.w);
      }
      Sm[m * 1024 + s * 8 + c] = sum;
    }
  }
  __syncthreads();
  float prod[8];
#pragma unroll
  for (int c = 0; c < 8; ++c)
    prod[c] = Sm[s * 8 + c] * Sm[1024 + s * 8 + c];
#pragma unroll
  for (int di = 0; di < 4; ++di) {
    const int i = i0 + di;
    float A1 = 0.f;
#pragma unroll
    for (int c = 0; c < 8; ++c)
      A1 = fmaf(fac[s * 512 + c * 64 + i], prod[c], A1);
    // {v,q,a}_res at flat offset p*65536: [i, s*8 + head] — keep cached
    F.out[p * 65536 + i * 1024 + s * 8 + c_head] = o[di] * (A1 * INV_SCALE);
  }
}

// scores body (r7/r8-proven mapping): thread (wid, ln) owns, per ii, the 16
// floats at flat (4*wid+k)*256 + 4*ln, k=0..3 -> every store instruction is
// a fully wave-contiguous 1KB (16 complete 64B lines), now NONTEMPORAL.
// No max-subtraction (logits sigma~1, max << 88, fp32 exp can't overflow);
// log2e folded into u[] so exp2f.
__device__ __forceinline__ void scores_body(const float* __restrict__ vp,
                                            const float* __restrict__ qp,
                                            const float* __restrict__ ap,
                                            float* __restrict__ out, int b,
                                            int t, float* SH) {
  const int s = b >> 4;
  const int i0 = (b & 15) * 4;
  float* tqL = SH;
  float* taL = SH + 512;
  float* uL = SH + 1024;                       // [ii][c]
  float(*redS)[4] = (float(*)[4])(SH + 1056);  // [ii][wid]
  if (t < 128)
    ((float4*)tqL)[t] = ((const float4*)(qp + s * 512))[t];
  else
    ((float4*)taL)[t - 128] = ((const float4*)(ap + s * 512))[t - 128];
  if (t < 32) {
    int ii = t >> 3, c = t & 7;
    uL[t] = vp[s * 512 + c * 64 + i0 + ii] * (INV_SCALE * LOG2E);
  }
  __syncthreads();
  const int wid = t >> 6, ln = t & 63;
  const int jb = 16 * wid + (ln >> 4);  // j for k=0 (then +4 per k)
  const int lq = (ln & 15) * 4;         // l base (4 consecutive l)
  float acc[4][16];                     // [ii][k*4+e]
#pragma unroll
  for (int ii = 0; ii < 4; ++ii)
#pragma unroll
    for (int x = 0; x < 16; ++x) acc[ii][x] = 0.f;
#pragma unroll
  for (int c = 0; c < 8; ++c) {
    const float* tq_c = &tqL[c * 64 + jb];
    float tj0 = tq_c[0];
    float tj1 = tq_c[4];
    float tj2 = tq_c[8];
    float tj3 = tq_c[12];
    float4 ta4 = *reinterpret_cast<const float4*>(&taL[c * 64 + lq]);
#pragma unroll
    for (int ii = 0; ii < 4; ++ii) {
      float uv = uL[ii * 8 + c];
      float m0 = uv * tj0;
      float m1 = uv * tj1;
      float m2 = uv * tj2;
      float m3 = uv * tj3;
      acc[ii][0] = fmaf(m0, ta4.x, acc[ii][0]);
      acc[ii][1] = fmaf(m0, ta4.y, acc[ii][1]);
      acc[ii][2] = fmaf(m0, ta4.z, acc[ii][2]);
      acc[ii][3] = fmaf(m0, ta4.w, acc[ii][3]);
      acc[ii][4] = fmaf(m1, ta4.x, acc[ii][4]);
      acc[ii][5] = fmaf(m1, ta4.y, acc[ii][5]);
      acc[ii][6] = fmaf(m1, ta4.z, acc[ii][6]);
      acc[ii][7] = fmaf(m1, ta4.w, acc[ii][7]);
      acc[ii][8] = fmaf(m2, ta4.x, acc[ii][8]);
      acc[ii][9] = fmaf(m2, ta4.y, acc[ii][9]);
      acc[ii][10] = fmaf(m2, ta4.z, acc[ii][10]);
      acc[ii][11] = fmaf(m2, ta4.w, acc[ii][11]);
      acc[ii][12] = fmaf(m3, ta4.x, acc[ii][12]);
      acc[ii][13] = fmaf(m3, ta4.y, acc[ii][13]);
      acc[ii][14] = fmaf(m3, ta4.z, acc[ii][14]);
      acc[ii][15] = fmaf(m3, ta4.w, acc[ii][15]);
    }
  }
#pragma unroll
  for (int ii = 0; ii < 4; ++ii) {
    float sl = 0.f;
#pragma unroll
    for (int x = 0; x < 16; ++x) {
      float e = exp2f(acc[ii][x]);  // acc carries log2e scaling
      acc[ii][x] = e;
      sl += e;
    }
#pragma unroll
    for (int o = 32; o; o >>= 1) sl += __shfl_xor(sl, o);
    if (ln == 0) redS[ii][wid] = sl;
  }
  __syncthreads();
  const long sbase = 262144L + (long)s * 262144 + (long)i0 * 4096;
#pragma unroll
  for (int ii = 0; ii < 4; ++ii) {
    float tot = (redS[ii][0] + redS[ii][1]) + (redS[ii][2] + redS[ii][3]);
    float sc = 1.0f / tot;
    // 4 stores, each wave-contiguous 1KB (full 64B lines) — NONTEMPORAL:
    // bypass L2 dirty-line churn; no RMW since lines are fully covered.
    float* ob = out + sbase + ii * 4096 + wid * 1024 + ln * 4;
#pragma unroll
    for (int k = 0; k < 4; ++k) {
      nat_f4 v = {acc[ii][k * 4 + 0] * sc, acc[ii][k * 4 + 1] * sc,
                  acc[ii][k * 4 + 2] * sc, acc[ii][k * 4 + 3] * sc};
      __builtin_nontemporal_store(v, reinterpret_cast<nat_f4*>(ob + k * 256));
    }
  }
}

__global__ __launch_bounds__(256) void fused_kernel(FusedArgs F) {
  __shared__ float SH[6160];  // 4096 (WL) + 16*129 (XT) = 24.6 KB
  const int b = blockIdx.x;
  if (b < 256)
    proj2_direct_body(F, b, threadIdx.x, SH);
  else
    scores_body(F.vp, F.qp, F.ap, F.out, b - 256, threadIdx.x, SH);
}

extern "C" void kernel_launch(void* const* d_in, const int* in_sizes, int n_in,
                              void* d_out, int out_size, void* d_ws, size_t ws_size,
                              hipStream_t stream) {
  // setup_inputs order: v,q,a,k, 4 masks (unused), then Wv,bv,Wq,bq,Wa,ba,Wk,bk,
  //                     Wvo,bvo,Wqo,bqo,Wao,bao,Wko,bko
  int wb = 8;
  if (n_in >= 5 && in_sizes[4] == 262144) wb = 4;  // defensive: masks absent
  const float* W[8];
  const float* B[8];
  for (int i = 0; i < 8; ++i) {
    W[i] = (const float*)d_in[wb + 2 * i];
    B[i] = (const float*)d_in[wb + 2 * i + 1];
  }
  float* ws = (float*)d_ws;
  float* vp = ws;
  float* qp = ws + 65536;
  float* ap = ws + 131072;
  float* kp = ws + 196608;
  float* out = (float*)d_out;

  // Stage 1: input projections (vp = v@Wv^T+bv, etc.) — 512 blocks, 2/CU
  Proj4Args a1;
  for (int i = 0; i < 4; ++i) {
    a1.x[i] = (const float*)d_in[i];
    a1.w[i] = W[i];
    a1.b[i] = B[i];
  }
  a1.y[0] = vp; a1.y[1] = qp; a1.y[2] = ap; a1.y[3] = kp;
  hipLaunchKernelGGL(proj4_kernel, dim3(512), dim3(256), 0, stream, a1);

  // Fused: stage-2 projections w/ direct final outputs (256) + scores (2048)
  FusedArgs F;
  for (int i = 0; i < 4; ++i) {
    F.w2[i] = W[4 + i];
    F.b2[i] = B[4 + i];
  }
  F.vp = vp; F.qp = qp; F.ap = ap; F.kp = kp; F.out = out;
  hipLaunchKernelGGL(fused_kernel, dim3(2304), dim3(256), 0, stream, F);
}

// Round 11
// 226.834 us; speedup vs baseline: 1.0080x; 1.0080x over previous
//
#include <hip/hip_runtime.h>

// Problem constants: S=128, D=512, H=8, W=64, NUM=16, SCALE=sqrt(8)
// All inputs and outputs fp32 (reference dtypes); fp32 compute throughout.
// FINAL configuration (r8, best = 224.3 us). Frozen empirical facts (r0-r10):
// - XT[k][*] k-major transpose staging is the fast GEMM staging idiom
//   (r1/r2: two "improved" layouts cost ~4x in proj4).
// - Fused packaging (proj2 + scores in ONE dispatch) is worth ~25 us (r3).
// - Scores occupancy is NOT the bottleneck (r4: +50% residency -> +0).
// - Nontemporal stores REGRESS both half-line (r6, RMW) and full-line (r10,
//   ~+4 us): L2 write-combining beats direct-to-HBM streaming here.
// - Wave-contiguous full-line 1KB stores are worth ~4 us (r7).
// - proj4 at 2 blocks/CU is worth ~5 us (r8: latency exposure at 1 blk/CU).
// - Barriers/phase-lock/desync are NOT the bottleneck (r9: wave-per-row -> 0).
// Ledger: ~161 us harness fills (immovable) + ~5 proj4 + ~59 fused.
#define INV_SCALE 0.35355339059327373f
#define LOG2E 1.4426950408889634f

struct Proj4Args {
  const float* x[4];
  const float* w[4];
  const float* b[4];
  float* y[4];
};

// ---------------------------------------------------------------------------
// Stage-1 projection GEMM, 512 blocks: blk = (p<<7)|(dt<<1)|sh.
// Block computes y[p][shalf*64 .. +64][dbase .. dbase+8]. 2 blocks/CU.
// ---------------------------------------------------------------------------
__global__ __launch_bounds__(256) void proj4_kernel(Proj4Args A) {
  __shared__ float SH[6176];  // 4096 (WL 8x512) + 2080 (XT[32][65])
  const int blk = blockIdx.x;
  const int p = blk >> 7;
  const int dbase = ((blk >> 1) & 63) * 8;
  const int shalf = (blk & 1) * 64;
  const int t = threadIdx.x;
  const int s = t & 63;
  const int g = t >> 6;  // wave id; di pair = g*2 (wave-uniform)
  float* WL = SH;
  float(*XT)[65] = (float(*)[65])(SH + 4096);
  {
    const float4* wg = (const float4*)(A.w[p] + dbase * 512);
    float4* wl4 = (float4*)WL;
#pragma unroll
    for (int r = 0; r < 4; ++r) wl4[t + r * 256] = wg[t + r * 256];
  }
  const float* xg = A.x[p] + shalf * 512;  // this block's 64 rows
  const int row = t >> 3;  // 0..31; +32 covers rows 0..63
  const int col = t & 7;   // float4 column within the 32-k chunk
  float acc[2] = {0.f, 0.f};
  float4 pre[2];
#pragma unroll
  for (int r = 0; r < 2; ++r)
    pre[r] = ((const float4*)(xg + (row + r * 32) * 512))[col];  // chunk 0
  for (int c = 0; c < 16; ++c) {
    __syncthreads();  // also covers the W stage at c==0
#pragma unroll
    for (int r = 0; r < 2; ++r) {
      float4 f = pre[r];
      int rr = row + r * 32;
      XT[col * 4 + 0][rr] = f.x;
      XT[col * 4 + 1][rr] = f.y;
      XT[col * 4 + 2][rr] = f.z;
      XT[col * 4 + 3][rr] = f.w;
    }
    __syncthreads();
    if (c + 1 < 16) {
#pragma unroll
      for (int r = 0; r < 2; ++r)
        pre[r] = ((const float4*)(xg + (row + r * 32) * 512))[(c + 1) * 8 + col];
    }
#pragma unroll
    for (int k4 = 0; k4 < 8; ++k4) {
      float xv0 = XT[k4 * 4 + 0][s];
      float xv1 = XT[k4 * 4 + 1][s];
      float xv2 = XT[k4 * 4 + 2][s];
      float xv3 = XT[k4 * 4 + 3][s];
#pragma unroll
      for (int di = 0; di < 2; ++di) {
        // wave-uniform address -> LDS broadcast read (free)
        const float4 wv =
            *(const float4*)&WL[(g * 2 + di) * 512 + c * 32 + k4 * 4];
        acc[di] = fmaf(wv.x, xv0, acc[di]);
        acc[di] = fmaf(wv.y, xv1, acc[di]);
        acc[di] = fmaf(wv.z, xv2, acc[di]);
        acc[di] = fmaf(wv.w, xv3, acc[di]);
      }
    }
  }
  const float* bp = A.b[p] + dbase + g * 2;
  *(float2*)(A.y[p] + (shalf + s) * 512 + dbase + g * 2) =
      make_float2(acc[0] + bp[0], acc[1] + bp[1]);
}

// ---------------------------------------------------------------------------
// GEMM body for proj2 (CHUNK=16 instantiation).
// ---------------------------------------------------------------------------
template <int CHUNK>
__device__ __forceinline__ void gemm8_body(const float* xg, const float* wg_p,
                                           const float* bp, int dbase, int t,
                                           float* SH, float o[4]) {
  const int s = t & 127;
  const int h = t >> 7;
  float* WL = SH;                                // [8][512] = 4096 floats
  float(*XT)[129] = (float(*)[129])(SH + 4096);  // [CHUNK][129]
  {
    const float4* wg = (const float4*)(wg_p + dbase * 512);
    float4* wl4 = (float4*)WL;
#pragma unroll
    for (int r = 0; r < 4; ++r) wl4[t + r * 256] = wg[t + r * 256];
  }
  constexpr int C4 = CHUNK / 4;     // float4 cols per chunk row
  constexpr int RPT = C4 / 2;       // row-groups per thread
  constexpr int NCH = 512 / CHUNK;  // number of k chunks
  constexpr int RSTEP = 256 / C4;   // row stride between r-groups
  const int row = t / C4;
  const int col = t % C4;
  float acc[4] = {0.f, 0.f, 0.f, 0.f};
  float4 pre[RPT];
#pragma unroll
  for (int r = 0; r < RPT; ++r)
    pre[r] = ((const float4*)(xg + (row + r * RSTEP) * 512))[col];  // chunk 0
  for (int c = 0; c < NCH; ++c) {
    __syncthreads();  // also covers the W stage at c==0
#pragma unroll
    for (int r = 0; r < RPT; ++r) {
      float4 f = pre[r];
      int rr = row + r * RSTEP;
      XT[col * 4 + 0][rr] = f.x;
      XT[col * 4 + 1][rr] = f.y;
      XT[col * 4 + 2][rr] = f.z;
      XT[col * 4 + 3][rr] = f.w;
    }
    __syncthreads();
    if (c + 1 < NCH) {
#pragma unroll
      for (int r = 0; r < RPT; ++r)
        pre[r] =
            ((const float4*)(xg + (row + r * RSTEP) * 512))[(c + 1) * C4 + col];
    }
#pragma unroll
    for (int k4 = 0; k4 < C4; ++k4) {
      float xv0 = XT[k4 * 4 + 0][s];
      float xv1 = XT[k4 * 4 + 1][s];
      float xv2 = XT[k4 * 4 + 2][s];
      float xv3 = XT[k4 * 4 + 3][s];
#pragma unroll
      for (int di = 0; di < 4; ++di) {
        // wave-uniform address -> LDS broadcast read (free)
        const float4 wv =
            *(const float4*)&WL[(h * 4 + di) * 512 + c * CHUNK + k4 * 4];
        acc[di] = fmaf(wv.x, xv0, acc[di]);
        acc[di] = fmaf(wv.y, xv1, acc[di]);
        acc[di] = fmaf(wv.z, xv2, acc[di]);
        acc[di] = fmaf(wv.w, xv3, acc[di]);
      }
    }
  }
#pragma unroll
  for (int di = 0; di < 4; ++di) o[di] = acc[di] + bp[dbase + h * 4 + di];
}

// ---------------------------------------------------------------------------
// Fused second launch.
//   blocks 0..255      -> stage-2 projection + DIRECT final-output epilogue
//   blocks 256..2303   -> scores (softmax att), needs stage-1 only
// ---------------------------------------------------------------------------
struct FusedArgs {
  const float* w2[4];  // Wvo,Wqo,Wao,Wko
  const float* b2[4];
  const float* vp;
  const float* qp;
  const float* ap;
  const float* kp;
  float* out;
};

__device__ __forceinline__ void proj2_direct_body(const FusedArgs& F, int blk,
                                                  int t, float* SH) {
  const int p = blk >> 6;
  const int dbase = (blk & 63) * 8;
  const float* xsrc[4] = {F.vp, F.qp, F.ap, F.kp};
  float o[4];
  gemm8_body<16>(xsrc[p], F.w2[p], F.b2[p], dbase, t, SH, o);
  const int s = t & 127;
  const int h = t >> 7;
  const int c_head = dbase >> 6;        // head index of this d-tile
  const int i0 = (dbase & 63) + h * 4;  // within-head coordinate base
  if (p == 3) {
    // k_res at flat offset 196608: [s, w*8 + head]
#pragma unroll
    for (int di = 0; di < 4; ++di)
      F.out[196608 + s * 512 + (i0 + di) * 8 + c_head] = o[di];
    return;  // p is block-uniform: no divergent-barrier hazard
  }
  const float* fac = (p == 0) ? F.vp : (p == 1) ? F.qp : F.kp;
  const float* S0 = (p == 0) ? F.qp : F.vp;
  const float* S1 = (p == 2) ? F.qp : F.kp;
  __syncthreads();  // all GEMM LDS reads done; reuse SH
  float* Sm = SH;   // [2][128][8] = 2048 floats
#pragma unroll
  for (int m = 0; m < 2; ++m) {
    const float* M = m ? S1 : S0;
#pragma unroll
    for (int cc = 0; cc < 4; ++cc) {
      const int c = h * 4 + cc;
      const float4* r4 = (const float4*)(M + s * 512 + c * 64);
      float sum = 0.f;
#pragma unroll
      for (int u = 0; u < 16; ++u) {
        float4 f = r4[u];
        sum += (f.x + f.y) + (f.z + f.w);
      }
      Sm[m * 1024 + s * 8 + c] = sum;
    }
  }
  __syncthreads();
  float prod[8];
#pragma unroll
  for (int c = 0; c < 8; ++c)
    prod[c] = Sm[s * 8 + c] * Sm[1024 + s * 8 + c];
#pragma unroll
  for (int di = 0; di < 4; ++di) {
    const int i = i0 + di;
    float A1 = 0.f;
#pragma unroll
    for (int c = 0; c < 8; ++c)
      A1 = fmaf(fac[s * 512 + c * 64 + i], prod[c], A1);
    // {v,q,a}_res at flat offset p*65536: [i, s*8 + head]
    F.out[p * 65536 + i * 1024 + s * 8 + c_head] = o[di] * (A1 * INV_SCALE);
  }
}

// scores body: thread (wid, ln) owns, per ii, the 16 floats at flat
// (4*wid+k)*256 + 4*ln, k=0..3 -> every store instruction is a fully
// wave-contiguous 1KB (16 complete 64B lines), normal cached stores.
// No max-subtraction (logits sigma~1, max << 88, fp32 exp can't overflow);
// log2e folded into u[] so exp2f.
__device__ __forceinline__ void scores_body(const float* __restrict__ vp,
                                            const float* __restrict__ qp,
                                            const float* __restrict__ ap,
                                            float* __restrict__ out, int b,
                                            int t, float* SH) {
  const int s = b >> 4;
  const int i0 = (b & 15) * 4;
  float* tqL = SH;
  float* taL = SH + 512;
  float* uL = SH + 1024;                       // [ii][c]
  float(*redS)[4] = (float(*)[4])(SH + 1056);  // [ii][wid]
  if (t < 128)
    ((float4*)tqL)[t] = ((const float4*)(qp + s * 512))[t];
  else
    ((float4*)taL)[t - 128] = ((const float4*)(ap + s * 512))[t - 128];
  if (t < 32) {
    int ii = t >> 3, c = t & 7;
    uL[t] = vp[s * 512 + c * 64 + i0 + ii] * (INV_SCALE * LOG2E);
  }
  __syncthreads();
  const int wid = t >> 6, ln = t & 63;
  const int jb = 16 * wid + (ln >> 4);  // j for k=0 (then +4 per k)
  const int lq = (ln & 15) * 4;         // l base (4 consecutive l)
  float acc[4][16];                     // [ii][k*4+e]
#pragma unroll
  for (int ii = 0; ii < 4; ++ii)
#pragma unroll
    for (int x = 0; x < 16; ++x) acc[ii][x] = 0.f;
#pragma unroll
  for (int c = 0; c < 8; ++c) {
    const float* tq_c = &tqL[c * 64 + jb];
    float tj0 = tq_c[0];
    float tj1 = tq_c[4];
    float tj2 = tq_c[8];
    float tj3 = tq_c[12];
    float4 ta4 = *reinterpret_cast<const float4*>(&taL[c * 64 + lq]);
#pragma unroll
    for (int ii = 0; ii < 4; ++ii) {
      float uv = uL[ii * 8 + c];
      float m0 = uv * tj0;
      float m1 = uv * tj1;
      float m2 = uv * tj2;
      float m3 = uv * tj3;
      acc[ii][0] = fmaf(m0, ta4.x, acc[ii][0]);
      acc[ii][1] = fmaf(m0, ta4.y, acc[ii][1]);
      acc[ii][2] = fmaf(m0, ta4.z, acc[ii][2]);
      acc[ii][3] = fmaf(m0, ta4.w, acc[ii][3]);
      acc[ii][4] = fmaf(m1, ta4.x, acc[ii][4]);
      acc[ii][5] = fmaf(m1, ta4.y, acc[ii][5]);
      acc[ii][6] = fmaf(m1, ta4.z, acc[ii][6]);
      acc[ii][7] = fmaf(m1, ta4.w, acc[ii][7]);
      acc[ii][8] = fmaf(m2, ta4.x, acc[ii][8]);
      acc[ii][9] = fmaf(m2, ta4.y, acc[ii][9]);
      acc[ii][10] = fmaf(m2, ta4.z, acc[ii][10]);
      acc[ii][11] = fmaf(m2, ta4.w, acc[ii][11]);
      acc[ii][12] = fmaf(m3, ta4.x, acc[ii][12]);
      acc[ii][13] = fmaf(m3, ta4.y, acc[ii][13]);
      acc[ii][14] = fmaf(m3, ta4.z, acc[ii][14]);
      acc[ii][15] = fmaf(m3, ta4.w, acc[ii][15]);
    }
  }
#pragma unroll
  for (int ii = 0; ii < 4; ++ii) {
    float sl = 0.f;
#pragma unroll
    for (int x = 0; x < 16; ++x) {
      float e = exp2f(acc[ii][x]);  // acc carries log2e scaling
      acc[ii][x] = e;
      sl += e;
    }
#pragma unroll
    for (int o = 32; o; o >>= 1) sl += __shfl_xor(sl, o);
    if (ln == 0) redS[ii][wid] = sl;
  }
  __syncthreads();
  const long sbase = 262144L + (long)s * 262144 + (long)i0 * 4096;
#pragma unroll
  for (int ii = 0; ii < 4; ++ii) {
    float tot = (redS[ii][0] + redS[ii][1]) + (redS[ii][2] + redS[ii][3]);
    float sc = 1.0f / tot;
    // 4 stores, each wave-contiguous 1KB: float4 at base + k*256 + ln*4
    float* ob = out + sbase + ii * 4096 + wid * 1024 + ln * 4;
#pragma unroll
    for (int k = 0; k < 4; ++k) {
      *reinterpret_cast<float4*>(ob + k * 256) =
          make_float4(acc[ii][k * 4 + 0] * sc, acc[ii][k * 4 + 1] * sc,
                      acc[ii][k * 4 + 2] * sc, acc[ii][k * 4 + 3] * sc);
    }
  }
}

__global__ __launch_bounds__(256) void fused_kernel(FusedArgs F) {
  __shared__ float SH[6160];  // 4096 (WL) + 16*129 (XT) = 24.6 KB
  const int b = blockIdx.x;
  if (b < 256)
    proj2_direct_body(F, b, threadIdx.x, SH);
  else
    scores_body(F.vp, F.qp, F.ap, F.out, b - 256, threadIdx.x, SH);
}

extern "C" void kernel_launch(void* const* d_in, const int* in_sizes, int n_in,
                              void* d_out, int out_size, void* d_ws, size_t ws_size,
                              hipStream_t stream) {
  // setup_inputs order: v,q,a,k, 4 masks (unused), then Wv,bv,Wq,bq,Wa,ba,Wk,bk,
  //                     Wvo,bvo,Wqo,bqo,Wao,bao,Wko,bko
  int wb = 8;
  if (n_in >= 5 && in_sizes[4] == 262144) wb = 4;  // defensive: masks absent
  const float* W[8];
  const float* B[8];
  for (int i = 0; i < 8; ++i) {
    W[i] = (const float*)d_in[wb + 2 * i];
    B[i] = (const float*)d_in[wb + 2 * i + 1];
  }
  float* ws = (float*)d_ws;
  float* vp = ws;
  float* qp = ws + 65536;
  float* ap = ws + 131072;
  float* kp = ws + 196608;
  float* out = (float*)d_out;

  // Stage 1: input projections (vp = v@Wv^T+bv, etc.) — 512 blocks, 2/CU
  Proj4Args a1;
  for (int i = 0; i < 4; ++i) {
    a1.x[i] = (const float*)d_in[i];
    a1.w[i] = W[i];
    a1.b[i] = B[i];
  }
  a1.y[0] = vp; a1.y[1] = qp; a1.y[2] = ap; a1.y[3] = kp;
  hipLaunchKernelGGL(proj4_kernel, dim3(512), dim3(256), 0, stream, a1);

  // Fused: stage-2 projections w/ direct final outputs (256) + scores (2048)
  FusedArgs F;
  for (int i = 0; i < 4; ++i) {
    F.w2[i] = W[4 + i];
    F.b2[i] = B[4 + i];
  }
  F.vp = vp; F.qp = qp; F.ap = ap; F.kp = kp; F.out = out;
  hipLaunchKernelGGL(fused_kernel, dim3(2304), dim3(256), 0, stream, F);
}